// Round 1
// baseline (438.397 us; speedup 1.0000x reference)
//
#include <hip/hip_runtime.h>

// Problem constants (from reference setup_inputs)
#define BB  16
#define TT  5
#define HH  256
#define WWW 256
#define CIN 3
#define FF  8
#define GG  32   // 4*F gate channels

// Tile: 32 wide x 8 tall, 256 threads, 1 pixel/thread
#define TW 32
#define TH 8

__device__ __forceinline__ float frcp(float x) { return __builtin_amdgcn_rcpf(x); }
__device__ __forceinline__ float fsigmoid(float x) { return frcp(1.0f + __expf(-x)); }
__device__ __forceinline__ float ftanh(float x) { return 1.0f - 2.0f * frcp(1.0f + __expf(2.0f * x)); }

// One fused ConvLSTM timestep:
//   z = conv3x3(x_t, Wx) + conv3x3(h, Wh) + bias; gates i,f,g,o; c,h update.
// FIRST=true: h=c=0 (skips recurrent conv + c read; never touches poisoned ws).
template <bool FIRST>
__global__ __launch_bounds__(256) void lstm_step(
    const float* __restrict__ xg,   // [B,T,H,W,CIN]
    int t,
    const float* __restrict__ wk,   // [3,3,CIN,GG]
    const float* __restrict__ wr,   // [3,3,FF,GG]
    const float* __restrict__ bias, // [GG]
    float* __restrict__ hbuf,       // [B,H,W,FF]
    float* __restrict__ cbuf)       // [B,H,W,FF]
{
    // halo tiles (+1 ring), h padded to 3 float4/pixel (48B pitch -> <=8-way bank alias)
    __shared__ float  xs[TH + 2][TW + 2][CIN];
    __shared__ float4 hs[TH + 2][TW + 2][3];

    const int tid = threadIdx.x;
    const int w0 = blockIdx.x * TW;
    const int h0 = blockIdx.y * TH;
    const int b  = blockIdx.z;

    // ---- stage x halo tile (zero-fill at borders, SAME padding) ----
    for (int l = tid; l < (TH + 2) * (TW + 2) * CIN; l += 256) {
        int r   = l / ((TW + 2) * CIN);
        int rem = l - r * ((TW + 2) * CIN);
        int c   = rem / CIN;
        int ch  = rem - c * CIN;
        int hh = h0 + r - 1, ww = w0 + c - 1;
        float v = 0.0f;
        if (hh >= 0 && hh < HH && ww >= 0 && ww < WWW)
            v = xg[(((size_t)(b * TT + t) * HH + hh) * WWW + ww) * CIN + ch];
        xs[r][c][ch] = v;
    }
    // ---- stage h halo tile ----
    if (!FIRST) {
        for (int l = tid; l < (TH + 2) * (TW + 2) * 2; l += 256) {
            int r   = l / ((TW + 2) * 2);
            int rem = l - r * ((TW + 2) * 2);
            int c   = rem >> 1;
            int q   = rem & 1;
            int hh = h0 + r - 1, ww = w0 + c - 1;
            float4 v = make_float4(0.f, 0.f, 0.f, 0.f);
            if (hh >= 0 && hh < HH && ww >= 0 && ww < WWW)
                v = *(const float4*)(hbuf + ((size_t)(b * HH + hh) * WWW + ww) * FF + q * 4);
            hs[r][c][q] = v;
        }
    }
    __syncthreads();

    const int ty = tid >> 5;   // 0..7
    const int tx = tid & 31;   // 0..31

    float acc[GG];
#pragma unroll
    for (int co = 0; co < GG; ++co) acc[co] = bias[co];

    // 3x3 taps; keep ky loop rolled to bound code size (~1/3 of full unroll)
#pragma unroll 1
    for (int ky = 0; ky < 3; ++ky) {
#pragma unroll
        for (int kx = 0; kx < 3; ++kx) {
            const int row = ty + ky, col = tx + kx;
            const float* wx = wk + (ky * 3 + kx) * CIN * GG;  // wave-uniform -> s_load
            float x0 = xs[row][col][0];
            float x1 = xs[row][col][1];
            float x2 = xs[row][col][2];
#pragma unroll
            for (int co = 0; co < GG; ++co)
                acc[co] = fmaf(x0, wx[co],
                          fmaf(x1, wx[GG + co],
                          fmaf(x2, wx[2 * GG + co], acc[co])));
            if (!FIRST) {
                float4 ha = hs[row][col][0];
                float4 hb = hs[row][col][1];
                float hv[FF] = {ha.x, ha.y, ha.z, ha.w, hb.x, hb.y, hb.z, hb.w};
                const float* wh = wr + (ky * 3 + kx) * FF * GG; // wave-uniform
#pragma unroll
                for (int ci = 0; ci < FF; ++ci) {
#pragma unroll
                    for (int co = 0; co < GG; ++co)
                        acc[co] = fmaf(hv[ci], wh[ci * GG + co], acc[co]);
                }
            }
        }
    }

    const int hh = h0 + ty, ww = w0 + tx;
    const size_t pix = (size_t)(b * HH + hh) * WWW + ww;

    float cold[FF] = {0.f, 0.f, 0.f, 0.f, 0.f, 0.f, 0.f, 0.f};
    if (!FIRST) {
        float4 c0 = *(const float4*)(cbuf + pix * FF);
        float4 c1 = *(const float4*)(cbuf + pix * FF + 4);
        cold[0] = c0.x; cold[1] = c0.y; cold[2] = c0.z; cold[3] = c0.w;
        cold[4] = c1.x; cold[5] = c1.y; cold[6] = c1.z; cold[7] = c1.w;
    }

    float cn[FF], hn[FF];
#pragma unroll
    for (int f = 0; f < FF; ++f) {
        float ig = fsigmoid(acc[f]);
        float fg = fsigmoid(acc[FF + f]);
        float g  = ftanh(acc[2 * FF + f]);
        float og = fsigmoid(acc[3 * FF + f]);
        float c  = fg * cold[f] + ig * g;
        cn[f] = c;
        hn[f] = og * ftanh(c);
    }

    *(float4*)(cbuf + pix * FF)     = make_float4(cn[0], cn[1], cn[2], cn[3]);
    *(float4*)(cbuf + pix * FF + 4) = make_float4(cn[4], cn[5], cn[6], cn[7]);
    *(float4*)(hbuf + pix * FF)     = make_float4(hn[0], hn[1], hn[2], hn[3]);
    *(float4*)(hbuf + pix * FF + 4) = make_float4(hn[4], hn[5], hn[6], hn[7]);
}

// BN(inference, eps=1e-3) -> LeakyReLU(0.3) -> Dense(F->2)
__global__ __launch_bounds__(256) void epilogue_kernel(
    const float* __restrict__ hbuf,
    const float* __restrict__ gamma, const float* __restrict__ beta,
    const float* __restrict__ mean,  const float* __restrict__ var,
    const float* __restrict__ dw,    const float* __restrict__ db,
    float* __restrict__ out)
{
    const size_t p = (size_t)blockIdx.x * 256 + threadIdx.x;  // < B*H*W
    float4 a = *(const float4*)(hbuf + p * FF);
    float4 bq = *(const float4*)(hbuf + p * FF + 4);
    float hv[FF] = {a.x, a.y, a.z, a.w, bq.x, bq.y, bq.z, bq.w};
    float o0 = db[0], o1 = db[1];
#pragma unroll
    for (int f = 0; f < FF; ++f) {
        float s = gamma[f] * rsqrtf(var[f] + 1e-3f);
        float x = (hv[f] - mean[f]) * s + beta[f];
        x = (x >= 0.f) ? x : 0.3f * x;
        o0 = fmaf(x, dw[f * 2 + 0], o0);
        o1 = fmaf(x, dw[f * 2 + 1], o1);
    }
    *(float2*)(out + p * 2) = make_float2(o0, o1);
}

extern "C" void kernel_launch(void* const* d_in, const int* in_sizes, int n_in,
                              void* d_out, int out_size, void* d_ws, size_t ws_size,
                              hipStream_t stream) {
    const float* x     = (const float*)d_in[0];
    const float* wk    = (const float*)d_in[1];
    const float* wr    = (const float*)d_in[2];
    const float* bias  = (const float*)d_in[3];
    const float* gamma = (const float*)d_in[4];
    const float* beta  = (const float*)d_in[5];
    const float* mean  = (const float*)d_in[6];
    const float* var   = (const float*)d_in[7];
    const float* dw    = (const float*)d_in[8];
    const float* db    = (const float*)d_in[9];
    float* out = (float*)d_out;

    const size_t state_elems = (size_t)BB * HH * WWW * FF;  // 8,388,608 floats
    float* cbuf = (float*)d_ws;
    float* hbuf = cbuf + state_elems;

    dim3 grid(WWW / TW, HH / TH, BB);  // (8, 32, 16)
    dim3 block(256);

    lstm_step<true><<<grid, block, 0, stream>>>(x, 0, wk, wr, bias, hbuf, cbuf);
    for (int t = 1; t < TT; ++t)
        lstm_step<false><<<grid, block, 0, stream>>>(x, t, wk, wr, bias, hbuf, cbuf);

    epilogue_kernel<<<(BB * HH * WWW) / 256, 256, 0, stream>>>(
        hbuf, gamma, beta, mean, var, dw, db, out);
}

// Round 4
// 276.693 us; speedup vs baseline: 1.5844x; 1.5844x over previous
//
#include <hip/hip_runtime.h>

// ConvLSTM2D (B=16,T=5,H=W=256,Cin=3,F=8) + BN + LeakyReLU + Dense(8->2)
// Convs as implicit GEMM on fp16 MFMA (16x16x32) with split-fp16 (hi/lo)
// precision recovery: z = xh*wh + xl*wh + xh*wl (residual O(2^-22)).
// fp32 gate math; c state fp32 (block-private custom layout, no race);
// h state fp16 PING-PONG buffered across timesteps (cross-block halo reads
// of a single-buffered h raced with same-step writes -> round2/3 failures).

#define BB  16
#define TT  5
#define HH  256
#define WW  256
#define CIN 3
#define FF  8
#define GG  32

#define TW  32   // tile width (pixels)
#define THT 16   // tile height
#define LW  34   // TW+2 halo
#define LH  18   // THT+2 halo

typedef _Float16 half8 __attribute__((ext_vector_type(8)));
typedef _Float16 half4 __attribute__((ext_vector_type(4)));
typedef float    floatx4 __attribute__((ext_vector_type(4)));

__device__ __forceinline__ float frcp(float x) { return __builtin_amdgcn_rcpf(x); }
__device__ __forceinline__ float fsig(float x) { return frcp(1.0f + __expf(-x)); }
__device__ __forceinline__ float ftanh_(float x) { return 1.0f - 2.0f * frcp(1.0f + __expf(2.0f * x)); }

#define MFMA(A, B, C) __builtin_amdgcn_mfma_f32_16x16x32_f16((A), (B), (C), 0, 0, 0)

// ---------------------------------------------------------------------------
// Setup: 10 B-fragments x {hi, lo}. MFMA B layout: n = lane&15, k = quad*8+j.
// K-chunks: 0: x taps0-7 (k=tap*4+ci, ci padded to 4)
//           1: x tap8   (k=ci, only k<3 nonzero)
//           2..4: h taps [4c..4c+3] (k=(tap-4c)*8+ci), taps>8 zero
// ---------------------------------------------------------------------------
__global__ void build_frags(const float* __restrict__ wk,
                            const float* __restrict__ wr,
                            _Float16* __restrict__ blob) {
    const int lane = threadIdx.x & 63;
    const int quad = lane >> 4, nlo = lane & 15;
    for (int chunk = 0; chunk < 5; ++chunk) {
        for (int nh = 0; nh < 2; ++nh) {
            const int n = nh * 16 + nlo;
            const int frag = chunk * 2 + nh;
            _Float16* dhi = blob + ((size_t)frag * 64 + lane) * 8;
            _Float16* dlo = blob + ((size_t)(10 + frag) * 64 + lane) * 8;
            for (int j = 0; j < 8; ++j) {
                const int k = quad * 8 + j;
                float w = 0.0f;
                if (chunk == 0) {                    // x conv, taps 0..7
                    int tap = k >> 2, ci = k & 3;
                    if (ci < 3) w = wk[(tap * 3 + ci) * GG + n];
                } else if (chunk == 1) {             // x conv, tap 8
                    if (quad == 0 && j < 3) w = wk[(8 * 3 + j) * GG + n];
                } else {                              // h conv
                    int c = chunk - 2;
                    int tap = c * 4 + quad, ci = j;
                    if (tap < 9) w = wr[(tap * FF + ci) * GG + n];
                }
                _Float16 wh = (_Float16)w;
                dhi[j] = wh;
                dlo[j] = (_Float16)(w - (float)wh);
            }
        }
    }
}

// ---------------------------------------------------------------------------
// One ConvLSTM timestep. Block = 256 threads (4 waves), tile 32x16 pixels.
// Reads h(t-1) from hin, writes h(t) to hout (ping-pong, race-free).
// ---------------------------------------------------------------------------
template <bool FIRST>
__global__ __launch_bounds__(256) void lstm_step(
    const float* __restrict__ xg,       // [B,T,H,W,3] fp32
    int t,
    const _Float16* __restrict__ blob,  // B-fragments (hi:0..9, lo:10..19)
    const float* __restrict__ bias,     // [32]
    const _Float16* __restrict__ hin,   // [B,H,W,8] fp16 (h at t-1)
    _Float16* __restrict__ hout,        // [B,H,W,8] fp16 (h at t)
    float* __restrict__ cbuf)           // [group][lane][2] fp32 (block-private)
{
    __shared__ half8 hls[LH * LW];     // h tile + halo
    __shared__ half4 xh_ls[LH * LW];   // x hi tile + halo (3ch + pad)
    __shared__ half4 xl_ls[LH * LW];   // x lo tile + halo

    const int tid  = threadIdx.x;
    const int bx = blockIdx.x, by = blockIdx.y, b = blockIdx.z;
    const int lane = tid & 63, wave = tid >> 6;
    const int quad = lane >> 4, nlo = lane & 15;

    // preload B-fragments (wave-replicated, L2-hot)
    half8 bfh[10], bfl[10];
#pragma unroll
    for (int i = 0; i < 10; ++i) {
        bfh[i] = *(const half8*)(blob + ((size_t)i * 64 + lane) * 8);
        bfl[i] = *(const half8*)(blob + ((size_t)(10 + i) * 64 + lane) * 8);
    }
    const float bv0 = bias[nlo], bv1 = bias[16 + nlo];

    // ---- stage x halo tile (fp32 -> fp16 hi + lo) ----
    for (int l = tid; l < LH * LW; l += 256) {
        int r = l / LW, c = l - r * LW;
        int gy = by * THT + r - 1, gx = bx * TW + c - 1;
        half4 vh = {(_Float16)0, (_Float16)0, (_Float16)0, (_Float16)0};
        half4 vl = vh;
        if ((unsigned)gy < HH && (unsigned)gx < WW) {
            const float* p = xg + (((size_t)(b * TT + t) * HH + gy) * WW + gx) * CIN;
#pragma unroll
            for (int ch = 0; ch < 3; ++ch) {
                float xv = p[ch];
                _Float16 xh = (_Float16)xv;
                vh[ch] = xh;
                vl[ch] = (_Float16)(xv - (float)xh);
            }
        }
        xh_ls[l] = vh;
        xl_ls[l] = vl;
    }
    // ---- stage h halo tile (fp16 direct, from PREVIOUS step's buffer) ----
    if (!FIRST) {
        for (int l = tid; l < LH * LW; l += 256) {
            int r = l / LW, c = l - r * LW;
            int gy = by * THT + r - 1, gx = bx * TW + c - 1;
            half8 v = {(_Float16)0, (_Float16)0, (_Float16)0, (_Float16)0,
                       (_Float16)0, (_Float16)0, (_Float16)0, (_Float16)0};
            if ((unsigned)gy < HH && (unsigned)gx < WW)
                v = *(const half8*)(hin + ((size_t)(b * HH + gy) * WW + gx) * FF);
            hls[l] = v;
        }
    }
    __syncthreads();

    const int gidbase = (((b * gridDim.y + by) * gridDim.x + bx) * 4 + wave) * 8;

    for (int g = 0; g < 8; ++g) {
        const int lr  = wave * 4 + (g >> 1);   // local row of this strip
        const int gx0 = (g & 1) * 16;          // strip start col
        const int lc  = gx0 + nlo;             // A-operand: m = lane&15 -> pixel col

        // ---- A fragments from LDS (hi and lo) ----
        const int t0 = 2 * quad, t1 = t0 + 1;
        const int i0 = (lr + t0 / 3) * LW + lc + t0 % 3;
        const int i1 = (lr + t1 / 3) * LW + lc + t1 % 3;
        const int i2 = (lr + 2) * LW + lc + 2;            // tap 8
        half8 a_xA_h, a_xB_h, a_xA_l, a_xB_l;
        {
            half4 p = xh_ls[i0], q = xh_ls[i1], s = xh_ls[i2];
            a_xA_h = (half8){p.x, p.y, p.z, p.w, q.x, q.y, q.z, q.w};
            a_xB_h = (half8){s.x, s.y, s.z, s.w, s.x, s.y, s.z, s.w};
        }
        {
            half4 p = xl_ls[i0], q = xl_ls[i1], s = xl_ls[i2];
            a_xA_l = (half8){p.x, p.y, p.z, p.w, q.x, q.y, q.z, q.w};
            a_xB_l = (half8){s.x, s.y, s.z, s.w, s.x, s.y, s.z, s.w};
        }

        floatx4 acc0 = {bv0, bv0, bv0, bv0};
        floatx4 acc1 = {bv1, bv1, bv1, bv1};
        // x conv: hi*hi + lo*hi + hi*lo
        acc0 = MFMA(a_xA_h, bfh[0], acc0);  acc1 = MFMA(a_xA_h, bfh[1], acc1);
        acc0 = MFMA(a_xB_h, bfh[2], acc0);  acc1 = MFMA(a_xB_h, bfh[3], acc1);
        acc0 = MFMA(a_xA_l, bfh[0], acc0);  acc1 = MFMA(a_xA_l, bfh[1], acc1);
        acc0 = MFMA(a_xB_l, bfh[2], acc0);  acc1 = MFMA(a_xB_l, bfh[3], acc1);
        acc0 = MFMA(a_xA_h, bfl[0], acc0);  acc1 = MFMA(a_xA_h, bfl[1], acc1);
        acc0 = MFMA(a_xB_h, bfl[2], acc0);  acc1 = MFMA(a_xB_h, bfl[3], acc1);
        if (!FIRST) {
#pragma unroll
            for (int c = 0; c < 3; ++c) {
                int tap = c * 4 + quad;
                if (tap > 8) tap = 8;                  // padded taps: B rows zero
                half8 ah = hls[(lr + tap / 3) * LW + lc + tap % 3];
                acc0 = MFMA(ah, bfh[4 + c * 2], acc0);
                acc1 = MFMA(ah, bfh[5 + c * 2], acc1);
                acc0 = MFMA(ah, bfl[4 + c * 2], acc0);
                acc1 = MFMA(ah, bfl[5 + c * 2], acc1);
            }
        }

        // ---- gate phase ----
        // C layout: pixel m = quad*4+reg, ch = lane&15 (acc0) / +16 (acc1).
        // Lanes c<8 hold (i,g), lanes c+8 hold (f,o): exchange via shfl_xor(8).
        const bool lo8 = (nlo < 8);
        float s0 = lo8 ? acc0[2] : acc0[0]; float r0 = __shfl_xor(s0, 8, 64);
        float s1 = lo8 ? acc0[3] : acc0[1]; float r1 = __shfl_xor(s1, 8, 64);
        float s2 = lo8 ? acc1[2] : acc1[0]; float r2 = __shfl_xor(s2, 8, 64);
        float s3 = lo8 ? acc1[3] : acc1[1]; float r3 = __shfl_xor(s3, 8, 64);

        const float zi0 = lo8 ? acc0[0] : r0, zi1 = lo8 ? acc0[1] : r1;
        const float zf0 = lo8 ? r0 : acc0[2], zf1 = lo8 ? r1 : acc0[3];
        const float zg0 = lo8 ? acc1[0] : r2, zg1 = lo8 ? acc1[1] : r3;
        const float zo0 = lo8 ? r2 : acc1[2], zo1 = lo8 ? r3 : acc1[3];

        float* cp = cbuf + ((size_t)(gidbase + g) * 64 + lane) * 2;
        float c0 = 0.0f, c1 = 0.0f;
        if (!FIRST) { float2 cc = *(const float2*)cp; c0 = cc.x; c1 = cc.y; }

        const float ii0 = fsig(zi0), ff0 = fsig(zf0), gg0 = ftanh_(zg0), oo0 = fsig(zo0);
        const float cn0 = ff0 * c0 + ii0 * gg0;
        const float hn0 = oo0 * ftanh_(cn0);
        const float ii1 = fsig(zi1), ff1 = fsig(zf1), gg1 = ftanh_(zg1), oo1 = fsig(zo1);
        const float cn1 = ff1 * c1 + ii1 * gg1;
        const float hn1 = oo1 * ftanh_(cn1);
        *(float2*)cp = make_float2(cn0, cn1);

        // h writeback: lane owns channel fc for 2 pixels (m0, m0+1)
        const int fc = nlo & 7;
        const int m0 = quad * 4 + (lo8 ? 0 : 2);
        const int gy = by * THT + lr;
        _Float16* hp = hout + ((size_t)(b * HH + gy) * WW + bx * TW + gx0 + m0) * FF + fc;
        hp[0]  = (_Float16)hn0;
        hp[FF] = (_Float16)hn1;
    }
}

// BN(eps=1e-3) -> LeakyReLU(0.3) -> Dense(8->2)
__global__ __launch_bounds__(256) void epilogue_kernel(
    const _Float16* __restrict__ hbuf,
    const float* __restrict__ gamma, const float* __restrict__ beta,
    const float* __restrict__ mean,  const float* __restrict__ var,
    const float* __restrict__ dw,    const float* __restrict__ db,
    float* __restrict__ out)
{
    const size_t p = (size_t)blockIdx.x * 256 + threadIdx.x;  // < B*H*W
    half8 hv8 = *(const half8*)(hbuf + p * FF);
    float o0 = db[0], o1 = db[1];
#pragma unroll
    for (int f = 0; f < FF; ++f) {
        float s = gamma[f] * rsqrtf(var[f] + 1e-3f);
        float x = ((float)hv8[f] - mean[f]) * s + beta[f];
        x = (x >= 0.f) ? x : 0.3f * x;
        o0 = fmaf(x, dw[f * 2 + 0], o0);
        o1 = fmaf(x, dw[f * 2 + 1], o1);
    }
    *(float2*)(out + p * 2) = make_float2(o0, o1);
}

extern "C" void kernel_launch(void* const* d_in, const int* in_sizes, int n_in,
                              void* d_out, int out_size, void* d_ws, size_t ws_size,
                              hipStream_t stream) {
    const float* x     = (const float*)d_in[0];
    const float* wk    = (const float*)d_in[1];
    const float* wr    = (const float*)d_in[2];
    const float* bias  = (const float*)d_in[3];
    const float* gamma = (const float*)d_in[4];
    const float* beta  = (const float*)d_in[5];
    const float* mean  = (const float*)d_in[6];
    const float* var   = (const float*)d_in[7];
    const float* dw    = (const float*)d_in[8];
    const float* db    = (const float*)d_in[9];
    float* out = (float*)d_out;

    // ws layout: blob (32 KB pad) | cbuf fp32 (33.55 MB) | h0 fp16 | h1 fp16
    const size_t state = (size_t)BB * HH * WW * FF;   // 8.39M elements
    _Float16* blob = (_Float16*)d_ws;
    float*    cbuf = (float*)((char*)d_ws + 32768);
    _Float16* h0   = (_Float16*)((char*)d_ws + 32768 + state * 4);
    _Float16* h1   = (_Float16*)((char*)h0 + state * 2);

    build_frags<<<1, 64, 0, stream>>>(wk, wr, blob);

    dim3 grid(WW / TW, HH / THT, BB);   // (8,16,16) = 2048 blocks
    dim3 block(256);
    // ping-pong: step t reads bufs[t&1], writes bufs[(t+1)&1]
    _Float16* bufs[2] = {h0, h1};
    lstm_step<true><<<grid, block, 0, stream>>>(x, 0, blob, bias, h0 /*unused*/, bufs[1], cbuf);
    for (int t = 1; t < TT; ++t)
        lstm_step<false><<<grid, block, 0, stream>>>(x, t, blob, bias, bufs[t & 1], bufs[(t + 1) & 1], cbuf);

    epilogue_kernel<<<(BB * HH * WW) / 256, 256, 0, stream>>>(
        bufs[TT & 1], gamma, beta, mean, var, dw, db, out);
}